// Round 10
// baseline (158.795 us; speedup 1.0000x reference)
//
#include <hip/hip_runtime.h>
#include <math.h>

#define HH 256
#define WW 256
#define NN (HH * WW)

typedef _Float16 f16;
typedef _Float16 f16x8 __attribute__((ext_vector_type(8)));
typedef _Float16 f16x4 __attribute__((ext_vector_type(4)));
typedef float f32x4 __attribute__((ext_vector_type(4)));

#define OQ 75264  // qkv B-frag base inside BF (f16 units)

// ---------------------------------------------------------------------------
// Prep (merged): blocks 0..511 convert x -> XH (NHWC f16 4ch);
// blocks 512..817 repack weights into MFMA B-fragments.
// BF layout: conv L0 @0 ([nt:3][lane][j]);
// L1 @1536, L2 @29184 ([tap:9][kc:2][nt:3][lane][j]);
// L3 @56832 ([tap:9][kc:2][nt:2][lane][j]);   <- tap-major: one tap's B-frags
// are a contiguous 6KB burst (R10: tap loop is no longer unrolled).
// qkv QF @OQ, KF @OQ+1024, VF @OQ+2048; total 78336 f16.
// ---------------------------------------------------------------------------
__global__ __launch_bounds__(256) void prep_kernel(
    const float* __restrict__ x, const float* __restrict__ w0,
    const float* __restrict__ w1, const float* __restrict__ w2,
    const float* __restrict__ w3, const float* __restrict__ qw,
    const float* __restrict__ kw, const float* __restrict__ vw,
    f16* __restrict__ xh, f16* __restrict__ bf) {
  if (blockIdx.x < 512) {
    int p = blockIdx.x * 256 + threadIdx.x;  // 0..2*NN-1
    int z = p >= NN;
    int q = p - z * NN;
    const float* xz = x + (size_t)z * 3 * NN;
    f16x4 v;
    v[0] = (f16)xz[q];
    v[1] = (f16)xz[NN + q];
    v[2] = (f16)xz[2 * NN + q];
    v[3] = (f16)0.f;
    *(f16x4*)(xh + (size_t)p * 4) = v;
    return;
  }
  const int O1 = 1536, O2 = O1 + 27648, O3 = O2 + 27648;
  int e = (blockIdx.x - 512) * 256 + threadIdx.x;
  if (e >= OQ + 3072) return;
  float val = 0.f;
  if (e >= OQ) {  // qkv B-frags
    int idx = e - OQ;
    int mat = idx >> 10;  // 0=Q 1=K 2=V
    int r = idx & 1023;
    int nt = r >> 9;
    int lane = (r >> 3) & 63;
    int j = r & 7;
    int n = lane & 15, quad = lane >> 4;
    int ci = quad * 8 + j, co = nt * 16 + n;
    const float* w = (mat == 0) ? qw : (mat == 1) ? kw : vw;
    if (ci < 24 && co < 24) val = w[co * 24 + ci];
  } else if (e < O1) {  // L0: [nt][lane][j]
    int idx = e;
    int j = idx & 7;
    int lane = (idx >> 3) & 63;
    int nt = idx >> 9;
    int n = lane & 15, quad = lane >> 4;
    int k = quad * 8 + j;
    int cout = nt * 16 + n;
    if (k < 27) {
      int tap = k / 3, ci = k - tap * 3;
      val = w0[(cout * 3 + ci) * 9 + tap];  // OIHW, tap = dy*3+dx
    }
  } else {  // L1/2/3: [tap][kc][nt][lane][j]
    const float* w;
    int COUT, idx;
    if (e < O2)      { w = w1; COUT = 48; idx = e - O1; }
    else if (e < O3) { w = w2; COUT = 48; idx = e - O2; }
    else             { w = w3; COUT = 24; idx = e - O3; }
    const int NT = (COUT == 48) ? 3 : 2;
    int j = idx & 7;
    int lane = (idx >> 3) & 63;
    int rest = idx >> 9;
    int nt = rest % NT;
    int q2 = rest / NT;
    int kc = q2 & 1;
    int tap = q2 >> 1;
    int n = lane & 15, quad = lane >> 4;
    int ci = kc * 32 + quad * 8 + j;
    int cout = nt * 16 + n;
    if (ci < 48 && cout < COUT) val = w[(cout * 48 + ci) * 9 + tap];
  }
  bf[e] = (f16)val;
}

// ---------------------------------------------------------------------------
// Layer 0: 3->48, K=27 padded to 32. Direct im2col A-panel in LDS.
// ---------------------------------------------------------------------------
__global__ __launch_bounds__(256, 2) void conv0_gemm(
    const f16* __restrict__ xh, const f16* __restrict__ bf0,
    const float* __restrict__ bias, f16* __restrict__ outh) {
  extern __shared__ char smem[];  // 256*80 B
  const int tid = threadIdx.x;
  const int lane = tid & 63, wave = tid >> 6;
  const int n = lane & 15, quad = lane >> 4;
  const int bx = blockIdx.x * 16, by = blockIdx.y * 16, z = blockIdx.z;
  const f16* xz = xh + (size_t)z * NN * 4;

  {
    int p = tid, y = p >> 4, xcol = p & 15;
    int gy = by + y, gx = bx + xcol;
    f16* row = (f16*)(smem + p * 80);
#pragma unroll
    for (int tap = 0; tap < 9; ++tap) {
      int dy = tap / 3, dx = tap - (tap / 3) * 3;
      int sy = gy + dy - 1, sx = gx + dx - 1;
      f16 c0 = (f16)0.f, c1 = c0, c2 = c0;
      if (sy >= 0 && sy < HH && sx >= 0 && sx < WW) {
        const f16* s = xz + ((size_t)sy * WW + sx) * 4;
        c0 = s[0]; c1 = s[1]; c2 = s[2];
      }
      row[tap * 3 + 0] = c0;
      row[tap * 3 + 1] = c1;
      row[tap * 3 + 2] = c2;
    }
#pragma unroll
    for (int k = 27; k < 32; ++k) row[k] = (f16)0.f;
  }
  __syncthreads();

  f32x4 acc[4][3];
#pragma unroll
  for (int nt = 0; nt < 3; ++nt) {
    float bv = bias[nt * 16 + n];
#pragma unroll
    for (int i = 0; i < 4; ++i) acc[i][nt] = (f32x4){bv, bv, bv, bv};
  }
  f16x8 B[3];
#pragma unroll
  for (int nt = 0; nt < 3; ++nt)
    B[nt] = *(const f16x8*)(bf0 + (nt * 64 + lane) * 8);
#pragma unroll
  for (int i = 0; i < 4; ++i) {
    int r = wave * 4 + i;
    f16x8 a = *(const f16x8*)(smem + (r * 16 + n) * 80 + quad * 16);
#pragma unroll
    for (int nt = 0; nt < 3; ++nt)
      acc[i][nt] =
          __builtin_amdgcn_mfma_f32_16x16x32_f16(a, B[nt], acc[i][nt], 0, 0, 0);
  }

  f16* oz = outh + (size_t)z * NN * 48;
#pragma unroll
  for (int i = 0; i < 4; ++i) {
    int y = by + wave * 4 + i;
#pragma unroll
    for (int nt = 0; nt < 3; ++nt)
#pragma unroll
      for (int reg = 0; reg < 4; ++reg)
        oz[((size_t)y * WW + bx + quad * 4 + reg) * 48 + nt * 16 + n] =
            (f16)fmaxf(acc[i][nt][reg], 0.f);
  }
}

// ---------------------------------------------------------------------------
// Layers 1-3 v2: 48->COUT implicit GEMM, restructured for occupancy.
// 16x8 px tile, grid (16,32,2) = 1024 blocks = 4/CU; halo 18x10 = 180 slots
// x 144B = 25.9 KB LDS; __launch_bounds__(256,4) caps VGPR at 128 (16
// waves/CU). Tap loop NOT unrolled (R9 failure theory: full 9-tap unroll +
// 256-VGPR cap let the scheduler hoist 54 B-loads -> spill/serialization).
// B-frags for one tap are one contiguous 6KB burst (BF tap-major).
// Wave w owns rows 2w..2w+1. FUSE: adds 1x1 skip, writes ABh (32ch/px f16).
// ---------------------------------------------------------------------------
template <int NT, int COUT, bool FUSE>
__global__ __launch_bounds__(256, 4) void gemm_conv(
    const f16* __restrict__ in, const f16* __restrict__ bfr,
    const float* __restrict__ bias, f16* __restrict__ outh,
    const float* __restrict__ xsrc, const float* __restrict__ skw,
    const float* __restrict__ skb) {
  extern __shared__ char smem[];           // 180*144 (+1.5KB xt if FUSE)
  float* xt = (float*)(smem + 180 * 144);  // [c:3][y:8][x:16]
  const int tid = threadIdx.x;
  const int lane = tid & 63, wave = tid >> 6;
  const int n = lane & 15, quad = lane >> 4;
  const int bx = blockIdx.x * 16, by = blockIdx.y * 8, z = blockIdx.z;
  const f16* inz = in + (size_t)z * NN * 48;

  if (tid < 180) {
    int p = tid;
    int yy = p / 18, xx = p - yy * 18;
    int gy = by + yy - 1, gx = bx + xx - 1;
    float4* dst = (float4*)(smem + p * 144);
    if (gy >= 0 && gy < HH && gx >= 0 && gx < WW) {
      const float4* s = (const float4*)(inz + ((size_t)gy * WW + gx) * 48);
      float4 a0 = s[0], a1 = s[1], a2 = s[2], a3 = s[3], a4 = s[4], a5 = s[5];
      dst[0] = a0; dst[1] = a1; dst[2] = a2;
      dst[3] = a3; dst[4] = a4; dst[5] = a5;
      dst[6] = make_float4(0, 0, 0, 0);
      dst[7] = make_float4(0, 0, 0, 0);
    } else {
      float4 zz = make_float4(0, 0, 0, 0);
#pragma unroll
      for (int c = 0; c < 8; ++c) dst[c] = zz;
    }
  }
  if (FUSE) {
    for (int i = tid; i < 384; i += 256) {
      int c = i >> 7, p = i & 127;
      xt[i] = xsrc[(size_t)z * 3 * NN + c * NN + (by + (p >> 4)) * WW + bx +
                   (p & 15)];
    }
  }
  __syncthreads();

  f32x4 acc[2][NT];
#pragma unroll
  for (int nt = 0; nt < NT; ++nt) {
    int cc = nt * 16 + n;
    float bv = (cc < COUT) ? bias[cc] : 0.f;
#pragma unroll
    for (int i = 0; i < 2; ++i) acc[i][nt] = (f32x4){bv, bv, bv, bv};
  }

  const int r0 = wave * 2;
#pragma unroll 1  // bounded live set: 6 B-frags + 2*NT acc + A-frags
  for (int tap = 0; tap < 9; ++tap) {
    const int dy = tap / 3, dx = tap - dy * 3;
    f16x8 B[2][NT];
#pragma unroll
    for (int kc = 0; kc < 2; ++kc)
#pragma unroll
      for (int nt = 0; nt < NT; ++nt)
        B[kc][nt] = *(const f16x8*)(bfr +
                                    (((tap * 2 + kc) * NT + nt) * 64 + lane) * 8);
#pragma unroll
    for (int i = 0; i < 2; ++i) {
      const int p = (r0 + i + dy) * 18 + (n + dx);
      const char* ap = smem + p * 144;
      f16x8 a0 = *(const f16x8*)(ap + quad * 16);
      f16x8 a1 = *(const f16x8*)(ap + 64 + quad * 16);
#pragma unroll
      for (int nt = 0; nt < NT; ++nt)
        acc[i][nt] = __builtin_amdgcn_mfma_f32_16x16x32_f16(a0, B[0][nt],
                                                            acc[i][nt], 0, 0, 0);
#pragma unroll
      for (int nt = 0; nt < NT; ++nt)
        acc[i][nt] = __builtin_amdgcn_mfma_f32_16x16x32_f16(a1, B[1][nt],
                                                            acc[i][nt], 0, 0, 0);
    }
  }

  if (!FUSE) {
    f16* oz = outh + (size_t)z * NN * 48;
#pragma unroll
    for (int i = 0; i < 2; ++i) {
      int y = by + r0 + i;
#pragma unroll
      for (int nt = 0; nt < NT; ++nt)
#pragma unroll
        for (int reg = 0; reg < 4; ++reg)
          oz[((size_t)y * WW + bx + quad * 4 + reg) * 48 + nt * 16 + n] =
              (f16)fmaxf(acc[i][nt][reg], 0.f);
    }
  } else {
    f16* oz = outh + (size_t)z * NN * 32;  // ABh stream base
#pragma unroll
    for (int i = 0; i < 2; ++i) {
      int y = by + r0 + i;
#pragma unroll
      for (int nt = 0; nt < NT; ++nt) {
        int cc = nt * 16 + n;
        float s0 = 0.f, s1 = 0.f, s2 = 0.f, sb0 = 0.f;
        if (cc < 24) {
          s0 = skw[cc * 3 + 0];
          s1 = skw[cc * 3 + 1];
          s2 = skw[cc * 3 + 2];
          sb0 = skb[cc];
        }
#pragma unroll
        for (int reg = 0; reg < 4; ++reg) {
          float v = 0.f;
          if (cc < 24) {
            int pl = (r0 + i) * 16 + quad * 4 + reg;
            float sk = sb0 + s0 * xt[pl] + s1 * xt[128 + pl] + s2 * xt[256 + pl];
            v = fmaxf(acc[i][nt][reg], 0.f) + sk;
          }
          oz[((size_t)(y * WW + bx + quad * 4 + reg)) * 32 + cc] = (f16)v;
        }
      }
    }
  }
}

// ---------------------------------------------------------------------------
// Q only. A-frag = one coalesced b128 from ABh-b.
// ---------------------------------------------------------------------------
__global__ __launch_bounds__(256) void q_mfma(const f16* __restrict__ ABh,
                                              const f16* __restrict__ bf,
                                              const float* __restrict__ qb,
                                              f16* __restrict__ Qh) {
  const int tid = threadIdx.x;
  const int lane = tid & 63, wave = tid >> 6;
  const int n = lane & 15, quad = lane >> 4;
  const f16* src = ABh + (size_t)NN * 32;  // stream b
  f16x8 QF[2];
#pragma unroll
  for (int nt = 0; nt < 2; ++nt)
    QF[nt] = *(const f16x8*)(bf + OQ + (nt * 64 + lane) * 8);
  float qbias[2];
#pragma unroll
  for (int nt = 0; nt < 2; ++nt) {
    int cc = nt * 16 + n;
    qbias[nt] = (cc < 24) ? qb[cc] : 0.f;
  }
#pragma unroll
  for (int t = 0; t < 4; ++t) {
    int T = blockIdx.x * 16 + wave * 4 + t;
    size_t p0 = (size_t)T * 16;
    f16x8 a8 = *(const f16x8*)(src + p0 * 32 + n * 32 + quad * 8);
#pragma unroll
    for (int nt = 0; nt < 2; ++nt) {
      f32x4 acc = {qbias[nt], qbias[nt], qbias[nt], qbias[nt]};
      acc = __builtin_amdgcn_mfma_f32_16x16x32_f16(a8, QF[nt], acc, 0, 0, 0);
      int cc = nt * 16 + n;
      if (cc < 24) {
#pragma unroll
        for (int reg = 0; reg < 4; ++reg)
          Qh[(p0 + quad * 4 + reg) * 24 + cc] = (f16)acc[reg];
      }
    }
  }
}

// ---------------------------------------------------------------------------
// Attention v3 (unchanged from R9). 32x8 px tile; a-halo staged then
// converted in place to K|V via MFMA; scores fdot2; PV packed-f16.
// ---------------------------------------------------------------------------
__device__ inline float dot8p(f16x8 a, f16x8 b, float acc) {
#if __has_builtin(__builtin_amdgcn_fdot2)
  acc = __builtin_amdgcn_fdot2(__builtin_shufflevector(a, a, 0, 1),
                               __builtin_shufflevector(b, b, 0, 1), acc, false);
  acc = __builtin_amdgcn_fdot2(__builtin_shufflevector(a, a, 2, 3),
                               __builtin_shufflevector(b, b, 2, 3), acc, false);
  acc = __builtin_amdgcn_fdot2(__builtin_shufflevector(a, a, 4, 5),
                               __builtin_shufflevector(b, b, 4, 5), acc, false);
  acc = __builtin_amdgcn_fdot2(__builtin_shufflevector(a, a, 6, 7),
                               __builtin_shufflevector(b, b, 6, 7), acc, false);
  return acc;
#else
#pragma unroll
  for (int i = 0; i < 8; ++i) acc += (float)a[i] * (float)b[i];
  return acc;
#endif
}

__global__ __launch_bounds__(256, 3) void attn_kernel(
    const f16* __restrict__ Qh, const f16* __restrict__ ABh,
    const f16* __restrict__ bf, const float* __restrict__ kb,
    const float* __restrict__ vb, float* __restrict__ out) {
  extern __shared__ f16 kv[];  // 544 slots * 56 f16 = 60928 B
  const int tid = threadIdx.x;
  const int lane = tid & 63, wave = tid >> 6;
  const int n16 = lane & 15, quad = lane >> 4;
  const int bx = blockIdx.x * 32, by = blockIdx.y * 8;
  const int xl = tid & 31, yl = tid >> 5;
  const int p = (by + yl) * WW + bx + xl;
  const f16* ah = ABh;                    // stream a
  const f16* bh = ABh + (size_t)NN * 32;  // stream b

  f16x8 q0 = *(const f16x8*)(Qh + (size_t)p * 24);
  f16x8 q1 = *(const f16x8*)(Qh + (size_t)p * 24 + 8);
  f16x8 q2 = *(const f16x8*)(Qh + (size_t)p * 24 + 16);

  for (int idx = tid; idx < 2128; idx += 256) {
    int row = idx / 152;
    int rem = idx - row * 152;
    int pxl = rem >> 2;
    int c = rem & 3;
    int gy = by + row - 3, gx = bx + pxl - 3;
    f16x8 v = {};
    if (gy >= 0 && gy < HH && gx >= 0 && gx < WW)
      v = *(const f16x8*)(ah + ((size_t)(gy * WW + gx)) * 32 + c * 8);
    *(f16x8*)(kv + (row * 38 + pxl) * 56 + c * 8) = v;
  }
  __syncthreads();

  const f16* cs = kv + ((yl + 3) * 38 + xl + 3) * 56;
  f16x8 a0 = *(const f16x8*)(cs);
  f16x8 a1 = *(const f16x8*)(cs + 8);
  f16x8 a2 = *(const f16x8*)(cs + 16);
  __syncthreads();

  {
    f16x8 KF[2], VF[2];
#pragma unroll
    for (int nt = 0; nt < 2; ++nt) {
      KF[nt] = *(const f16x8*)(bf + OQ + 1024 + (nt * 64 + lane) * 8);
      VF[nt] = *(const f16x8*)(bf + OQ + 2048 + (nt * 64 + lane) * 8);
    }
    float kbias[2], vbias[2];
#pragma unroll
    for (int nt = 0; nt < 2; ++nt) {
      int cc = nt * 16 + n16;
      kbias[nt] = (cc < 24) ? kb[cc] : 0.f;
      vbias[nt] = (cc < 24) ? vb[cc] : 0.f;
    }
    for (int t = wave; t < 34; t += 4) {
      f16x8 a8 = *(const f16x8*)(kv + (t * 16 + n16) * 56 + quad * 8);
#pragma unroll
      for (int nt = 0; nt < 2; ++nt) {
        f32x4 ak = {kbias[nt], kbias[nt], kbias[nt], kbias[nt]};
        f32x4 av = {vbias[nt], vbias[nt], vbias[nt], vbias[nt]};
        ak = __builtin_amdgcn_mfma_f32_16x16x32_f16(a8, KF[nt], ak, 0, 0, 0);
        av = __builtin_amdgcn_mfma_f32_16x16x32_f16(a8, VF[nt], av, 0, 0, 0);
        int cc = nt * 16 + n16;
        if (cc < 24) {
#pragma unroll
          for (int reg = 0; reg < 4; ++reg) {
            f16* slot = kv + (t * 16 + quad * 4 + reg) * 56;
            slot[cc] = (f16)ak[reg];       // K at f16 [0:24)
            slot[24 + cc] = (f16)av[reg];  // V at f16 [24:48)
          }
        }
      }
    }
  }
  __syncthreads();

  float s[49];
#pragma unroll
  for (int pp = 0; pp < 49; ++pp) {
    int dy = pp / 7, dx = pp - dy * 7;
    const f16* base = kv + ((yl + dy) * 38 + xl + dx) * 56;
    f16x8 k0 = *(const f16x8*)(base);
    f16x8 k1 = *(const f16x8*)(base + 8);
    f16x8 k2 = *(const f16x8*)(base + 16);
    float d = 0.f;
    d = dot8p(q0, k0, d);
    d = dot8p(q1, k1, d);
    d = dot8p(q2, k2, d);
    s[pp] = d * 0.20412414523193154f;  // 1/sqrt(24)
  }

  float m = s[0];
#pragma unroll
  for (int pp = 1; pp < 49; ++pp) m = fmaxf(m, s[pp]);
  float den = 0.f;
#pragma unroll
  for (int pp = 0; pp < 49; ++pp) {
    float e = __expf(s[pp] - m);
    s[pp] = e;
    den += e;
  }
  const float inv = 1.f / den;

  f16x8 y0 = {}, y1 = {}, y2 = {};
#pragma unroll
  for (int pp = 0; pp < 49; ++pp) {
    int dy = pp / 7, dx = pp - dy * 7;
    const f16* base = kv + ((yl + dy) * 38 + xl + dx) * 56 + 24;
    f16 wh = (f16)(s[pp] * inv);
    f16x8 w8 = {wh, wh, wh, wh, wh, wh, wh, wh};
    f16x8 v0 = *(const f16x8*)(base);
    f16x8 v1 = *(const f16x8*)(base + 8);
    f16x8 v2 = *(const f16x8*)(base + 16);
    y0 = v0 * w8 + y0;
    y1 = v1 * w8 + y1;
    y2 = v2 * w8 + y2;
  }

  f16x8 b0 = *(const f16x8*)(bh + (size_t)p * 32);
  f16x8 b1 = *(const f16x8*)(bh + (size_t)p * 32 + 8);
  f16x8 b2 = *(const f16x8*)(bh + (size_t)p * 32 + 16);
#pragma unroll
  for (int c = 0; c < 8; ++c) {
    out[(size_t)c * NN + p] = (float)y0[c] + (float)a0[c];
    out[(size_t)(8 + c) * NN + p] = (float)y1[c] + (float)a1[c];
    out[(size_t)(16 + c) * NN + p] = (float)y2[c] + (float)a2[c];
    out[(size_t)(24 + c) * NN + p] = (float)b0[c];
    out[(size_t)(32 + c) * NN + p] = (float)b1[c];
    out[(size_t)(40 + c) * NN + p] = (float)b2[c];
  }
}

// ---------------------------------------------------------------------------
extern "C" void kernel_launch(void* const* d_in, const int* in_sizes, int n_in,
                              void* d_out, int out_size, void* d_ws,
                              size_t ws_size, hipStream_t stream) {
  const float* x = (const float*)d_in[0];
  const float* w0 = (const float*)d_in[1];
  const float* b0 = (const float*)d_in[2];
  const float* w1 = (const float*)d_in[3];
  const float* b1 = (const float*)d_in[4];
  const float* w2 = (const float*)d_in[5];
  const float* b2 = (const float*)d_in[6];
  const float* w3 = (const float*)d_in[7];
  const float* b3 = (const float*)d_in[8];
  const float* sw = (const float*)d_in[9];
  const float* sb = (const float*)d_in[10];
  const float* qw = (const float*)d_in[11];
  const float* qb = (const float*)d_in[12];
  const float* kw = (const float*)d_in[13];
  const float* kb = (const float*)d_in[14];
  const float* vw = (const float*)d_in[15];
  const float* vb = (const float*)d_in[16];
  float* out = (float*)d_out;
  float* ws = (float*)d_ws;

  // workspace layout (float units), all regions disjoint:
  f16* Qh = (f16*)(ws);                       // NN*24 f16 = 12*NN floats
  f16* ABh = (f16*)(ws + (size_t)12 * NN);    // 2*NN*32 f16 = 32*NN floats
  f16* ACT0 = (f16*)(ws + (size_t)44 * NN);   // 2*NN*48 f16 = 48*NN floats
  f16* ACT1 = (f16*)(ws + (size_t)92 * NN);   // 48*NN floats
  f16* XH = (f16*)(ws + (size_t)140 * NN);    // 4*NN floats
  f16* BF = (f16*)(ws + (size_t)144 * NN);    // 78336 f16

  prep_kernel<<<dim3(818), dim3(256), 0, stream>>>(x, w0, w1, w2, w3, qw, kw,
                                                   vw, XH, BF);

  conv0_gemm<<<dim3(16, 16, 2), dim3(256), 256 * 80, stream>>>(XH, BF, b0,
                                                               ACT0);
  dim3 g2(16, 32, 2);  // 16x8 px tiles, 1024 blocks = 4/CU
  gemm_conv<3, 48, false><<<g2, dim3(256), 180 * 144, stream>>>(
      ACT0, BF + 1536, b1, ACT1, nullptr, nullptr, nullptr);
  gemm_conv<3, 48, false><<<g2, dim3(256), 180 * 144, stream>>>(
      ACT1, BF + 29184, b2, ACT0, nullptr, nullptr, nullptr);
  gemm_conv<2, 24, true><<<g2, dim3(256), 180 * 144 + 1536, stream>>>(
      ACT0, BF + 56832, b3, ABh, x, sw, sb);

  q_mfma<<<dim3(256), dim3(256), 0, stream>>>(ABh, BF, qb, Qh);

  attn_kernel<<<dim3(8, 32), dim3(256), 544 * 112, stream>>>(Qh, ABh, BF, kb,
                                                             vb, out);
}